// Round 7
// baseline (261.779 us; speedup 1.0000x reference)
//
#include <hip/hip_runtime.h>
#include <hip/hip_bf16.h>
#include <math.h>

#define BB 8
#define TT 2048
#define CC 1024
#define HH 64
#define NROW (BB*TT)          // 16384
#define NST (NROW*HH)         // 1048576 elements per output component
#define KK2 2048              // combined GEMM K = 2C
#define NN 384                // Bt rows (6 components)
#define GN 256                // G cols: [kr|ki|qr|qi]  (512 B rows, exact lines)
#define VTP 2080              // VT row stride in elements (4160 B, breaks 4KB aliasing)

typedef __attribute__((ext_vector_type(8))) short short8;
typedef __attribute__((ext_vector_type(4))) float f32x4;

static __device__ inline unsigned pk_bf16(float a, float b) {
    __hip_bfloat162 h = __float22bfloat162_rn(make_float2(a, b));
    unsigned u; __builtin_memcpy(&u, &h, 4); return u;
}
static __device__ inline short f2bf_s(float a) {
    __hip_bfloat16 h = __float2bfloat16(a);
    short s; __builtin_memcpy(&s, &h, 2); return s;
}
static __device__ inline short8 neg8(short8 a) {
    short8 r;
    #pragma unroll
    for (int i = 0; i < 8; ++i) r[i] = a[i] ^ (short)0x8000;
    return r;
}

// async global->LDS, 16B per lane; LDS dest is WAVE-UNIFORM base (HW adds lane*16)
static __device__ inline void async16(const void* g, void* l) {
    __builtin_amdgcn_global_load_lds(
        (const __attribute__((address_space(1))) void*)g,
        (__attribute__((address_space(3))) void*)l,
        16, 0, 0);
}

// ---------------------------------------------------------------------------
// Kernel 0: build Bt[n][k] bf16. n = 64*g + h, g in [kr,ki,qr,qi,vr,vi];
// real: [Wr;-Wi], imag: [Wi;Wr].
// ---------------------------------------------------------------------------
__global__ __launch_bounds__(256) void prep_kernel(
    const float* __restrict__ Wkr, const float* __restrict__ Wki,
    const float* __restrict__ Wqr, const float* __restrict__ Wqi,
    const float* __restrict__ Wvr, const float* __restrict__ Wvi,
    short* __restrict__ Bt)
{
    const int n = blockIdx.x;
    const int g = n >> 6, h = n & 63;
    const int p = g >> 1;
    const bool im = g & 1;
    const float* Wr = (p == 0) ? Wkr : (p == 1) ? Wqr : Wvr;
    const float* Wi = (p == 0) ? Wki : (p == 1) ? Wqi : Wvi;
    const float* W1 = im ? Wi : Wr;
    const float* W2 = im ? Wr : Wi;
    const float s2 = im ? 1.f : -1.f;

    #pragma unroll
    for (int j = 0; j < 8; ++j) {
        int k = threadIdx.x + 256 * j;
        float v = (k < CC) ? W1[k * HH + h] : s2 * W2[(k - CC) * HH + h];
        Bt[(size_t)n * KK2 + k] = f2bf_s(v);
    }
}

// ---------------------------------------------------------------------------
// Kernel 1: bf16 MFMA GEMM, fp32 A via global_load_lds, PHASE-PIPELINED
// (T3/T4 counted vmcnt). BM=128 BN=64, grid (128,6), 64 phases of K=32.
// Per phase: A [128][32] fp32 (16 KB) + B [64][32] bf16 (4 KB), double-
// buffered (40 KB total -> 3 blocks/CU, 768 blocks exactly co-resident).
// Pipeline: stage(ph+2) issued after compute(ph) frees its buffer; top-of-
// phase wait is s_waitcnt vmcnt(5) (retires exactly stage(ph)'s 5 in-order
// issues; stage(ph+1) stays in flight ACROSS the barrier). vmcnt never
// drains to 0 in the loop -> DMA has a full phase to land.
// Swizzles (content-permuting, both-sides involution):
//   A: chunk^(row&7) over 8x16B chunks/row  -> conflict-free per octet
//   B: chunk^((row>>1)&3) over 4x16B chunks -> all 32 banks distinct/octet
// ---------------------------------------------------------------------------
#define LDP 72    // epilogue G staging stride (elements)
#define STP 136   // epilogue sT row stride (elements), 16B-aligned
#define APH (128*32)   // fp32 elements per A phase buffer
#define BPH (64*32)    // bf16 elements per B phase buffer

__global__ __launch_bounds__(256) void proj_gemm(
    const float* __restrict__ xr, const float* __restrict__ xi,
    const short* __restrict__ Bt,
    short* __restrict__ G, short* __restrict__ VT)
{
    __shared__ __attribute__((aligned(16))) float sA[2 * APH];  // 32 KB
    __shared__ __attribute__((aligned(16))) short sB[2 * BPH];  // 8 KB

    const int tid = threadIdx.x;
    const int mbase = blockIdx.x * 128;
    const int comp = blockIdx.y;                 // 0..5

    const int wave = tid >> 6, lane = tid & 63;
    const int quad = lane >> 4, lm = lane & 15;

    // A staging: issue q covers rows q*8..q*8+7 (1 KB); lane -> row q*8+(lane>>3),
    // dest chunk lane&7; source chunk XOR-swizzled by row&7.
    const int arow = lane >> 3;                  // 0..7
    const int asrc = (lane & 7) ^ arow;          // swizzled source chunk
    // B staging: 1 issue/wave covers rows wave*16..+15; lane -> row +(lane>>2),
    // dest chunk lane&3; source chunk XOR-swizzled by (row>>1)&3.
    const int brow = lane >> 2;                  // 0..15
    const int bsrc = (lane & 3) ^ ((lane >> 3) & 3);

    const char* Bg = (const char*)(Bt + (size_t)comp * 64 * KK2);

    f32x4 acc[2][4] = {};

    #define STAGE_PH(ph, BUF) do {                                              \
        const int ks_ = (ph) >> 1;                                              \
        const float* __restrict__ sa_ = (ks_ < 16) ? xr : xi;                   \
        const int kc_ = (ks_ & 15) * 64 + ((ph) & 1) * 32;                      \
        _Pragma("unroll")                                                       \
        for (int i_ = 0; i_ < 4; ++i_) {                                        \
            int q_ = wave * 4 + i_;                                             \
            int r_ = q_ * 8 + arow;                                             \
            async16((const char*)(sa_ + (size_t)(mbase + r_) * CC + kc_)        \
                        + (asrc << 4),                                          \
                    (char*)(sA + (BUF) * APH) + q_ * 1024);                     \
        }                                                                       \
        async16(Bg + (size_t)(wave * 16 + brow) * (KK2 * 2)                     \
                    + ks_ * 128 + ((ph) & 1) * 64 + (bsrc << 4),                \
                (char*)(sB + (BUF) * BPH) + wave * 1024);                       \
    } while (0)

    #define COMPUTE_PH(BUF) do {                                                \
        const float* sAp_ = sA + (BUF) * APH;                                   \
        const short* sBp_ = sB + (BUF) * BPH;                                   \
        short8 af_[2];                                                          \
        _Pragma("unroll")                                                       \
        for (int mi_ = 0; mi_ < 2; ++mi_) {                                     \
            const int row_ = 32 * wave + 16 * mi_ + lm;                         \
            const int s_ = lm & 7;                                              \
            f32x4 a0_ = *(const f32x4*)&sAp_[row_ * 32 + (((2*quad)   ^ s_) << 2)]; \
            f32x4 a1_ = *(const f32x4*)&sAp_[row_ * 32 + (((2*quad+1) ^ s_) << 2)]; \
            uint4 u_;                                                           \
            u_.x = pk_bf16(a0_[0], a0_[1]);                                     \
            u_.y = pk_bf16(a0_[2], a0_[3]);                                     \
            u_.z = pk_bf16(a1_[0], a1_[1]);                                     \
            u_.w = pk_bf16(a1_[2], a1_[3]);                                     \
            __builtin_memcpy(&af_[mi_], &u_, 16);                               \
        }                                                                       \
        short8 bf_[4];                                                          \
        _Pragma("unroll")                                                       \
        for (int ni_ = 0; ni_ < 4; ++ni_)                                       \
            bf_[ni_] = *(const short8*)&sBp_[(16 * ni_ + lm) * 32               \
                        + ((quad ^ ((lm >> 1) & 3)) << 3)];                     \
        _Pragma("unroll")                                                       \
        for (int mi_ = 0; mi_ < 2; ++mi_)                                       \
            _Pragma("unroll")                                                   \
            for (int ni_ = 0; ni_ < 4; ++ni_)                                   \
                acc[mi_][ni_] = __builtin_amdgcn_mfma_f32_16x16x32_bf16(        \
                    af_[mi_], bf_[ni_], acc[mi_][ni_], 0, 0, 0);                \
    } while (0)

    // ---- prologue: stage phases 0 and 1 (10 issues in flight) ----
    STAGE_PH(0, 0);
    STAGE_PH(1, 1);

    // ---- main loop: 2 phases per iteration, buffers as literals ----
    for (int ph = 0; ph < 62; ph += 2) {
        asm volatile("s_waitcnt vmcnt(5)" ::: "memory");   // retire stage(ph)
        __builtin_amdgcn_s_barrier();
        __builtin_amdgcn_sched_barrier(0);
        COMPUTE_PH(0);
        __builtin_amdgcn_sched_barrier(0);
        __builtin_amdgcn_s_barrier();                      // buf0 free
        STAGE_PH(ph + 2, 0);

        asm volatile("s_waitcnt vmcnt(5)" ::: "memory");   // retire stage(ph+1)
        __builtin_amdgcn_s_barrier();
        __builtin_amdgcn_sched_barrier(0);
        COMPUTE_PH(1);
        __builtin_amdgcn_sched_barrier(0);
        __builtin_amdgcn_s_barrier();                      // buf1 free
        STAGE_PH(ph + 3, 1);
    }
    // ---- peeled phases 62, 63 ----
    asm volatile("s_waitcnt vmcnt(5)" ::: "memory");       // retire stage(62)
    __builtin_amdgcn_s_barrier();
    __builtin_amdgcn_sched_barrier(0);
    COMPUTE_PH(0);
    asm volatile("s_waitcnt vmcnt(0)" ::: "memory");       // retire stage(63)
    __builtin_amdgcn_s_barrier();
    __builtin_amdgcn_sched_barrier(0);
    COMPUTE_PH(1);

    __syncthreads();   // epilogue: safe to reuse LDS

    // ---- epilogue: wave w owns output rows 32w..32w+31, cols 0..63 ----
    if (comp < 4) {
        short* sG = (short*)sA;   // [128][LDP] = 18.4 KB <= 32 KB
        #pragma unroll
        for (int mi = 0; mi < 2; ++mi)
            #pragma unroll
            for (int ni = 0; ni < 4; ++ni)
                #pragma unroll
                for (int r = 0; r < 4; ++r)
                    sG[(32*wave + 16*mi + quad*4 + r) * LDP + 16*ni + lm] =
                        f2bf_s(acc[mi][ni][r]);
        __syncthreads();
        #pragma unroll
        for (int j = 0; j < 4; ++j) {
            int id = tid + 256 * j;
            int row = id >> 3, c8 = id & 7;       // 8 x 16B per row
            uint4 v = *(const uint4*)&sG[row * LDP + c8 * 8];
            *(uint4*)&G[(size_t)(mbase + row) * GN + comp*64 + c8*8] = v;
        }
    } else {
        short* sT = (short*)sA;   // [64][STP] = 17.4 KB <= 32 KB
        const int vcomp = comp - 4;
        const int b = mbase >> 11;
        const int tb = mbase & 2047;
        #pragma unroll
        for (int mi = 0; mi < 2; ++mi)
            #pragma unroll
            for (int ni = 0; ni < 4; ++ni)
                #pragma unroll
                for (int r = 0; r < 4; ++r)
                    sT[(16*ni + lm) * STP + 32*wave + 16*mi + quad*4 + r] =
                        f2bf_s(acc[mi][ni][r]);
        __syncthreads();
        #pragma unroll
        for (int j = 0; j < 4; ++j) {
            int id = tid + 256 * j;
            int h = id >> 4, c = id & 15;         // 16 x 16B per h-row
            uint4 v = *(const uint4*)&sT[h * STP + c * 8];
            *(uint4*)&VT[(((size_t)vcomp*BB + b)*64 + h)*VTP + tb + c*8] = v;
        }
    }
    #undef STAGE_PH
    #undef COMPUTE_PH
}

// ---------------------------------------------------------------------------
// Kernel 2: MFMA flash attention, log2-domain online softmax.
// Grid is (b, j): linear bid % 8 == b -> all blocks of batch b on XCD b,
// K/V panels stay L2-resident (FETCH 6.2 MB measured, was 34.6).
// ---------------------------------------------------------------------------
#define PLDS 72
#define SC2 0.18033688f      // 0.125 * log2(e): softmax in exp2 domain

__global__ __launch_bounds__(256) void attn_kernel(
    const short* __restrict__ G,
    const short* __restrict__ VT,
    float* __restrict__ out)
{
    __shared__ float comb[4][16][128];
    __shared__ float cmw[4][16], clw[4][16];

    const int tid = threadIdx.x;
    const int wave = tid >> 6, lane = tid & 63;
    const int quad = lane >> 4, lm = lane & 15;
    const int b = blockIdx.x;                               // XCD affinity: bid%8 == b
    const int j = (int)(gridDim.y - 1) - (int)blockIdx.y;   // longest first
    const int qbase = j * 16;
    const int nkt = (j >> 2) + 1;    // k-tiles of 64 tokens

    const short* Qrow = G + ((size_t)(b*TT + qbase + lm)) * GN + 128;
    short8 A1[4], A2[4];
    #pragma unroll
    for (int ks = 0; ks < 4; ++ks)
        A1[ks] = *(const short8*)(Qrow + ks*32 + quad*8);
    A2[0] = A1[2]; A2[1] = A1[3];
    A2[2] = neg8(A1[0]); A2[3] = neg8(A1[1]);

    short8 ones;
    #pragma unroll
    for (int i = 0; i < 8; ++i) ones[i] = (short)0x3F80;   // bf16 1.0

    f32x4 Or[4], Oi[4];
    #pragma unroll
    for (int h = 0; h < 4; ++h)
        #pragma unroll
        for (int r = 0; r < 4; ++r) { Or[h][r] = 0.f; Oi[h][r] = 0.f; }
    f32x4 Ol = {0.f, 0.f, 0.f, 0.f};            // row-sums via ones-MFMA
    float m[4];
    #pragma unroll
    for (int r = 0; r < 4; ++r) m[r] = -INFINITY;

    short* Pw = (short*)&comb[wave][0][0];
    const short* Vrb = VT + (size_t)b * 64 * VTP;
    const short* Vib = VT + ((size_t)BB + b) * 64 * VTP;

    for (int kt = wave; kt < nkt; kt += 4) {
        const int kb = kt * 64;
        const short* Kt = G + ((size_t)(b*TT + kb)) * GN;

        // ---- hoist ALL K loads: one latency exposure instead of 4 ----
        short8 Kf[4][4];
        #pragma unroll
        for (int nt = 0; nt < 4; ++nt) {
            const short* Krow = Kt + (size_t)(nt*16 + lm) * GN;
            #pragma unroll
            for (int ks = 0; ks < 4; ++ks)
                Kf[nt][ks] = *(const short8*)(Krow + ks*32 + quad*8);
        }

        f32x4 mag[4];
        #pragma unroll
        for (int nt = 0; nt < 4; ++nt) {
            f32x4 sr = {0.f,0.f,0.f,0.f}, si = {0.f,0.f,0.f,0.f};
            __builtin_amdgcn_s_setprio(1);
            #pragma unroll
            for (int ks = 0; ks < 4; ++ks) {
                sr = __builtin_amdgcn_mfma_f32_16x16x32_bf16(A1[ks], Kf[nt][ks], sr, 0,0,0);
                si = __builtin_amdgcn_mfma_f32_16x16x32_bf16(A2[ks], Kf[nt][ks], si, 0,0,0);
            }
            __builtin_amdgcn_s_setprio(0);
            int tok = kb + nt*16 + lm;
            #pragma unroll
            for (int r = 0; r < 4; ++r) {
                float v = __builtin_amdgcn_sqrtf(
                              fmaf(sr[r], sr[r], fmaf(si[r], si[r], 1e-4f))) * SC2;
                int qrow = qbase + quad*4 + r;
                mag[nt][r] = (tok > qrow) ? -INFINITY : v;
            }
        }

        // ---- issue V loads now; softmax below hides their latency ----
        short8 Vr[4][2], Vi[4][2];
        #pragma unroll
        for (int ht = 0; ht < 4; ++ht) {
            const short* vr0 = Vrb + (size_t)(ht*16 + lm) * VTP + kb + quad*8;
            const short* vi0 = Vib + (size_t)(ht*16 + lm) * VTP + kb + quad*8;
            Vr[ht][0] = *(const short8*)(vr0);
            Vr[ht][1] = *(const short8*)(vr0 + 32);
            Vi[ht][0] = *(const short8*)(vi0);
            Vi[ht][1] = *(const short8*)(vi0 + 32);
        }

        float tm[4];
        #pragma unroll
        for (int r = 0; r < 4; ++r)
            tm[r] = fmaxf(fmaxf(mag[0][r], mag[1][r]), fmaxf(mag[2][r], mag[3][r]));
        #pragma unroll
        for (int d = 1; d < 16; d <<= 1)
            #pragma unroll
            for (int r = 0; r < 4; ++r)
                tm[r] = fmaxf(tm[r], __shfl_xor(tm[r], d, 16));

        // defer-max: rescale only when the running max actually grows past slack
        int need = (tm[0] > m[0] + 8.f) | (tm[1] > m[1] + 8.f) |
                   (tm[2] > m[2] + 8.f) | (tm[3] > m[3] + 8.f);
        if (__any(need)) {
            float al[4];
            #pragma unroll
            for (int r = 0; r < 4; ++r) {
                float mn = fmaxf(m[r], tm[r]);
                al[r] = __builtin_amdgcn_exp2f(m[r] - mn);
                m[r] = mn;
            }
            #pragma unroll
            for (int h = 0; h < 4; ++h)
                #pragma unroll
                for (int r = 0; r < 4; ++r) { Or[h][r] *= al[r]; Oi[h][r] *= al[r]; }
            #pragma unroll
            for (int r = 0; r < 4; ++r) Ol[r] *= al[r];
        }

        #pragma unroll
        for (int nt = 0; nt < 4; ++nt)
            #pragma unroll
            for (int r = 0; r < 4; ++r) {
                float p = __builtin_amdgcn_exp2f(mag[nt][r] - m[r]);
                Pw[(quad*4 + r) * PLDS + nt*16 + lm] = f2bf_s(p);
            }
        short8 Af0 = *(const short8*)&Pw[lm * PLDS + quad*8];
        short8 Af1 = *(const short8*)&Pw[lm * PLDS + 32 + quad*8];

        __builtin_amdgcn_s_setprio(1);
        Ol = __builtin_amdgcn_mfma_f32_16x16x32_bf16(Af0, ones, Ol, 0,0,0);
        Ol = __builtin_amdgcn_mfma_f32_16x16x32_bf16(Af1, ones, Ol, 0,0,0);
        __builtin_amdgcn_s_setprio(0);

        #pragma unroll
        for (int ht = 0; ht < 4; ++ht) {
            __builtin_amdgcn_s_setprio(1);
            Or[ht] = __builtin_amdgcn_mfma_f32_16x16x32_bf16(Af0, Vr[ht][0], Or[ht], 0,0,0);
            Or[ht] = __builtin_amdgcn_mfma_f32_16x16x32_bf16(Af1, Vr[ht][1], Or[ht], 0,0,0);
            Oi[ht] = __builtin_amdgcn_mfma_f32_16x16x32_bf16(Af0, Vi[ht][0], Oi[ht], 0,0,0);
            Oi[ht] = __builtin_amdgcn_mfma_f32_16x16x32_bf16(Af1, Vi[ht][1], Oi[ht], 0,0,0);
            __builtin_amdgcn_s_setprio(0);
        }
    }

    __syncthreads();

    #pragma unroll
    for (int ht = 0; ht < 4; ++ht)
        #pragma unroll
        for (int r = 0; r < 4; ++r) {
            comb[wave][quad*4 + r][ht*16 + lm]      = Or[ht][r];
            comb[wave][quad*4 + r][64 + ht*16 + lm] = Oi[ht][r];
        }
    if (lm == 0) {
        #pragma unroll
        for (int r = 0; r < 4; ++r) {
            cmw[wave][quad*4 + r] = m[r];
            clw[wave][quad*4 + r] = Ol[r];
        }
    }
    __syncthreads();

    for (int e = tid; e < 16*128; e += 256) {
        int q = e >> 7, h = e & 127;
        float mstar = fmaxf(fmaxf(cmw[0][q], cmw[1][q]), fmaxf(cmw[2][q], cmw[3][q]));
        float osum = 0.f, lsum = 0.f;
        #pragma unroll
        for (int w = 0; w < 4; ++w) {
            float f = __builtin_amdgcn_exp2f(cmw[w][q] - mstar);
            osum = fmaf(f, comb[w][q][h], osum);
            lsum = fmaf(f, clw[w][q], lsum);
        }
        float res = osum / lsum;
        int comp = h >> 6, hh = h & 63;
        out[(size_t)comp * NST + ((size_t)(b*TT + qbase + q)) * HH + hh] = res;
    }
}

extern "C" void kernel_launch(void* const* d_in, const int* in_sizes, int n_in,
                              void* d_out, int out_size, void* d_ws, size_t ws_size,
                              hipStream_t stream)
{
    const float* xr  = (const float*)d_in[0];
    const float* xi  = (const float*)d_in[1];
    const float* Wkr = (const float*)d_in[2];
    const float* Wki = (const float*)d_in[3];
    const float* Wqr = (const float*)d_in[4];
    const float* Wqi = (const float*)d_in[5];
    const float* Wvr = (const float*)d_in[6];
    const float* Wvi = (const float*)d_in[7];

    short* Bt = (short*)d_ws;                               // 1.5 MB
    short* G  = (short*)((char*)d_ws + (2u  << 20));        // 8 MB  [16384][256]
    short* VT = (short*)((char*)d_ws + (11u << 20));        // 4.3 MB [2][8][64][VTP]
    float* out = (float*)d_out;

    prep_kernel<<<NN, 256, 0, stream>>>(Wkr, Wki, Wqr, Wqi, Wvr, Wvi, Bt);

    dim3 g1(NROW / 128, 6);
    proj_gemm<<<g1, 256, 0, stream>>>(xr, xi, Bt, G, VT);

    dim3 g3(BB, TT / 16);   // bid%8 == b -> per-batch XCD affinity
    attn_kernel<<<g3, 256, 0, stream>>>(G, VT, out);
}

// Round 8
// 242.365 us; speedup vs baseline: 1.0801x; 1.0801x over previous
//
#include <hip/hip_runtime.h>
#include <hip/hip_bf16.h>
#include <math.h>

#define BB 8
#define TT 2048
#define CC 1024
#define HH 64
#define NROW (BB*TT)          // 16384
#define NST (NROW*HH)         // 1048576 elements per output component
#define KK2 2048              // combined GEMM K = 2C
#define NN 384                // Bt rows (6 components)
#define GN 256                // G cols: [kr|ki|qr|qi]  (512 B rows, exact lines)
#define VTP 2080              // VT row stride in elements (4160 B, breaks 4KB aliasing)

typedef __attribute__((ext_vector_type(8))) short short8;
typedef __attribute__((ext_vector_type(4))) float f32x4;

static __device__ inline unsigned pk_bf16(float a, float b) {
    __hip_bfloat162 h = __float22bfloat162_rn(make_float2(a, b));
    unsigned u; __builtin_memcpy(&u, &h, 4); return u;
}
static __device__ inline short f2bf_s(float a) {
    __hip_bfloat16 h = __float2bfloat16(a);
    short s; __builtin_memcpy(&s, &h, 2); return s;
}
static __device__ inline short8 neg8(short8 a) {
    short8 r;
    #pragma unroll
    for (int i = 0; i < 8; ++i) r[i] = a[i] ^ (short)0x8000;
    return r;
}

// async global->LDS, 16B per lane; LDS dest is WAVE-UNIFORM base (HW adds lane*16)
static __device__ inline void async16(const void* g, void* l) {
    __builtin_amdgcn_global_load_lds(
        (const __attribute__((address_space(1))) void*)g,
        (__attribute__((address_space(3))) void*)l,
        16, 0, 0);
}

// ---------------------------------------------------------------------------
// Kernel 0: build Bt[n][k] bf16. n = 64*g + h, g in [kr,ki,qr,qi,vr,vi];
// real: [Wr;-Wi], imag: [Wi;Wr].
// ---------------------------------------------------------------------------
__global__ __launch_bounds__(256) void prep_kernel(
    const float* __restrict__ Wkr, const float* __restrict__ Wki,
    const float* __restrict__ Wqr, const float* __restrict__ Wqi,
    const float* __restrict__ Wvr, const float* __restrict__ Wvi,
    short* __restrict__ Bt)
{
    const int n = blockIdx.x;
    const int g = n >> 6, h = n & 63;
    const int p = g >> 1;
    const bool im = g & 1;
    const float* Wr = (p == 0) ? Wkr : (p == 1) ? Wqr : Wvr;
    const float* Wi = (p == 0) ? Wki : (p == 1) ? Wqi : Wvi;
    const float* W1 = im ? Wi : Wr;
    const float* W2 = im ? Wr : Wi;
    const float s2 = im ? 1.f : -1.f;

    #pragma unroll
    for (int j = 0; j < 8; ++j) {
        int k = threadIdx.x + 256 * j;
        float v = (k < CC) ? W1[k * HH + h] : s2 * W2[(k - CC) * HH + h];
        Bt[(size_t)n * KK2 + k] = f2bf_s(v);
    }
}

// ---------------------------------------------------------------------------
// Kernel 1: bf16 MFMA GEMM, fp32 A staged DIRECTLY via global_load_lds
// (R6-proven version, 70.6 us). BM=128 BN=64 BK=64, grid (128,6).
// Plain 2-barrier K-loop; 4x1 wave layout; A fp32 LDS tile read once with
// cvt_pk on the read side; B bf16 via async16 (proven R3 path).
// ---------------------------------------------------------------------------
#define LDP 72    // epilogue G staging stride (elements)
#define STP 136   // epilogue sT row stride (elements), 16B-aligned

__global__ __launch_bounds__(256) void proj_gemm(
    const float* __restrict__ xr, const float* __restrict__ xi,
    const short* __restrict__ Bt,
    short* __restrict__ G, short* __restrict__ VT)
{
    __shared__ __attribute__((aligned(16))) float sAf[128 * 64];  // 32 KB fp32 A
    __shared__ __attribute__((aligned(16))) short sB[64 * 64];    // 8 KB bf16 B

    const int tid = threadIdx.x;
    const int mbase = blockIdx.x * 128;
    const int comp = blockIdx.y;                 // 0..5

    const int wave = tid >> 6, lane = tid & 63;
    const int quad = lane >> 4, lm = lane & 15;

    // B staging lane decomposition: 8 lanes x 16B cover one 128B row
    const int lgrp = lane >> 3;                  // row within 8-row group
    const int lslot = lane & 7;
    const int scolB = ((lslot ^ lgrp) << 4);     // swizzled byte col within row

    // A staging: per issue q (=wave*8+i), 1 KB = 4 fp32-rows of 256 B.
    const int arow_l = lane >> 4;                // 0..3
    const int acol_l = lane & 15;                // chunk slot 0..15

    const char* Bg = (const char*)(Bt + (size_t)comp * 64 * KK2);

    f32x4 acc[2][4] = {};

    for (int ks = 0; ks < KK2 / 64; ++ks) {
        const float* __restrict__ srcA = (ks < 16) ? xr : xi;
        const int kc = (ks & 15) * 64;

        // ---- A: 8 async16 per wave (32 KB tile) ----
        #pragma unroll
        for (int i = 0; i < 8; ++i) {
            int q = wave * 8 + i;
            int r = q * 4 + arow_l;
            int c = acol_l ^ (r & 7);            // swizzled source chunk
            async16((const char*)(srcA + (size_t)(mbase + r) * CC + kc) + (c << 4),
                    (char*)sAf + q * 1024);
        }
        // ---- B: 2 async16 per wave (8 KB tile) ----
        #pragma unroll
        for (int i = 0; i < 2; ++i) {
            int q = wave * 2 + i;
            async16(Bg + (size_t)(q * 8 + lgrp) * (KK2 * 2) + ks * 128 + scolB,
                    (char*)sB + q * 1024);
        }
        __syncthreads();   // drains vmcnt -> tile resident

        #pragma unroll
        for (int kk = 0; kk < 2; ++kk) {
            // A frags: rows 32*wave + 16*mi + lm, fp32 cols kk*32+quad*8..+7
            short8 af[2];
            #pragma unroll
            for (int mi = 0; mi < 2; ++mi) {
                const int row = 32 * wave + 16 * mi + lm;
                const int c0 = 8 * kk + 2 * quad;
                const int s = row & 7;
                f32x4 a0 = *(const f32x4*)&sAf[row * 64 + ((c0 ^ s) << 2)];
                f32x4 a1 = *(const f32x4*)&sAf[row * 64 + (((c0 + 1) ^ s) << 2)];
                uint4 u;
                u.x = pk_bf16(a0[0], a0[1]);
                u.y = pk_bf16(a0[2], a0[3]);
                u.z = pk_bf16(a1[0], a1[1]);
                u.w = pk_bf16(a1[2], a1[3]);
                __builtin_memcpy(&af[mi], &u, 16);
            }
            // B frags: rows 16*ni + lm (bf16), un-swizzled on read
            const int cs = (kk * 32 + quad * 8) ^ ((lm & 7) << 3);
            short8 bf[4];
            #pragma unroll
            for (int ni = 0; ni < 4; ++ni)
                bf[ni] = *(const short8*)&sB[(16 * ni + lm) * 64 + cs];

            #pragma unroll
            for (int mi = 0; mi < 2; ++mi)
                #pragma unroll
                for (int ni = 0; ni < 4; ++ni)
                    acc[mi][ni] = __builtin_amdgcn_mfma_f32_16x16x32_bf16(
                        af[mi], bf[ni], acc[mi][ni], 0, 0, 0);
        }
        __syncthreads();   // LDS reads done before next stage overwrites
    }

    // ---- epilogue: wave w owns output rows 32w..32w+31, cols 0..63 ----
    if (comp < 4) {
        short* sG = (short*)sAf;   // [128][LDP] = 18.4 KB <= 32 KB
        #pragma unroll
        for (int mi = 0; mi < 2; ++mi)
            #pragma unroll
            for (int ni = 0; ni < 4; ++ni)
                #pragma unroll
                for (int r = 0; r < 4; ++r)
                    sG[(32*wave + 16*mi + quad*4 + r) * LDP + 16*ni + lm] =
                        f2bf_s(acc[mi][ni][r]);
        __syncthreads();
        #pragma unroll
        for (int j = 0; j < 4; ++j) {
            int id = tid + 256 * j;
            int row = id >> 3, c8 = id & 7;       // 8 x 16B per row
            uint4 v = *(const uint4*)&sG[row * LDP + c8 * 8];
            *(uint4*)&G[(size_t)(mbase + row) * GN + comp*64 + c8*8] = v;
        }
    } else {
        short* sT = (short*)sAf;   // [64][STP] = 17.4 KB <= 32 KB
        const int vcomp = comp - 4;
        const int b = mbase >> 11;
        const int tb = mbase & 2047;
        #pragma unroll
        for (int mi = 0; mi < 2; ++mi)
            #pragma unroll
            for (int ni = 0; ni < 4; ++ni)
                #pragma unroll
                for (int r = 0; r < 4; ++r)
                    sT[(16*ni + lm) * STP + 32*wave + 16*mi + quad*4 + r] =
                        f2bf_s(acc[mi][ni][r]);
        __syncthreads();
        #pragma unroll
        for (int j = 0; j < 4; ++j) {
            int id = tid + 256 * j;
            int h = id >> 4, c = id & 15;         // 16 x 16B per h-row
            uint4 v = *(const uint4*)&sT[h * STP + c * 8];
            *(uint4*)&VT[(((size_t)vcomp*BB + b)*64 + h)*VTP + tb + c*8] = v;
        }
    }
}

// ---------------------------------------------------------------------------
// Kernel 2: MFMA flash attention, log2-domain online softmax.
// LOAD-BALANCED: grid (8 b, 64); block y processes q-tiles j=127-y THEN j=y.
// Per-block work = nkt(127-y)+nkt(y) = 33 +/- 1 (was 1..32) -> every CU gets
// identical work, no straggler tail (old per-CU spread was 52..83 iterations
// with the longest blocks finishing at ~1 wave/SIMD occupancy).
// XCD affinity preserved: bid%8 == b -> batch panels stay L2-resident.
// ---------------------------------------------------------------------------
#define PLDS 72
#define SC2 0.18033688f      // 0.125 * log2(e): softmax in exp2 domain

__global__ __launch_bounds__(256) void attn_kernel(
    const short* __restrict__ G,
    const short* __restrict__ VT,
    float* __restrict__ out)
{
    __shared__ float comb[4][16][128];
    __shared__ float cmw[4][16], clw[4][16];

    const int tid = threadIdx.x;
    const int wave = tid >> 6, lane = tid & 63;
    const int quad = lane >> 4, lm = lane & 15;
    const int b = blockIdx.x;                    // XCD affinity: bid%8 == b
    const int y = blockIdx.y;                    // 0..63

    short8 ones;
    #pragma unroll
    for (int i = 0; i < 8; ++i) ones[i] = (short)0x3F80;   // bf16 1.0

    short* Pw = (short*)&comb[wave][0][0];
    const short* Vrb = VT + (size_t)b * 64 * VTP;
    const short* Vib = VT + ((size_t)BB + b) * 64 * VTP;

    for (int half = 0; half < 2; ++half) {
        const int j = half ? y : (127 - y);      // long tile first
        const int qbase = j * 16;
        const int nkt = (j >> 2) + 1;            // k-tiles of 64 tokens

        const short* Qrow = G + ((size_t)(b*TT + qbase + lm)) * GN + 128;
        short8 A1[4], A2[4];
        #pragma unroll
        for (int ks = 0; ks < 4; ++ks)
            A1[ks] = *(const short8*)(Qrow + ks*32 + quad*8);
        A2[0] = A1[2]; A2[1] = A1[3];
        A2[2] = neg8(A1[0]); A2[3] = neg8(A1[1]);

        f32x4 Or[4], Oi[4];
        #pragma unroll
        for (int h = 0; h < 4; ++h)
            #pragma unroll
            for (int r = 0; r < 4; ++r) { Or[h][r] = 0.f; Oi[h][r] = 0.f; }
        f32x4 Ol = {0.f, 0.f, 0.f, 0.f};         // row-sums via ones-MFMA
        float m[4];
        #pragma unroll
        for (int r = 0; r < 4; ++r) m[r] = -INFINITY;

        for (int kt = wave; kt < nkt; kt += 4) {
            const int kb = kt * 64;
            const short* Kt = G + ((size_t)(b*TT + kb)) * GN;

            // ---- hoist ALL K loads: one latency exposure instead of 4 ----
            short8 Kf[4][4];
            #pragma unroll
            for (int nt = 0; nt < 4; ++nt) {
                const short* Krow = Kt + (size_t)(nt*16 + lm) * GN;
                #pragma unroll
                for (int ks = 0; ks < 4; ++ks)
                    Kf[nt][ks] = *(const short8*)(Krow + ks*32 + quad*8);
            }

            f32x4 mag[4];
            #pragma unroll
            for (int nt = 0; nt < 4; ++nt) {
                f32x4 sr = {0.f,0.f,0.f,0.f}, si = {0.f,0.f,0.f,0.f};
                __builtin_amdgcn_s_setprio(1);
                #pragma unroll
                for (int ks = 0; ks < 4; ++ks) {
                    sr = __builtin_amdgcn_mfma_f32_16x16x32_bf16(A1[ks], Kf[nt][ks], sr, 0,0,0);
                    si = __builtin_amdgcn_mfma_f32_16x16x32_bf16(A2[ks], Kf[nt][ks], si, 0,0,0);
                }
                __builtin_amdgcn_s_setprio(0);
                int tok = kb + nt*16 + lm;
                #pragma unroll
                for (int r = 0; r < 4; ++r) {
                    float v = __builtin_amdgcn_sqrtf(
                                  fmaf(sr[r], sr[r], fmaf(si[r], si[r], 1e-4f))) * SC2;
                    int qrow = qbase + quad*4 + r;
                    mag[nt][r] = (tok > qrow) ? -INFINITY : v;
                }
            }

            // ---- issue V loads now; softmax below hides their latency ----
            short8 Vr[4][2], Vi[4][2];
            #pragma unroll
            for (int ht = 0; ht < 4; ++ht) {
                const short* vr0 = Vrb + (size_t)(ht*16 + lm) * VTP + kb + quad*8;
                const short* vi0 = Vib + (size_t)(ht*16 + lm) * VTP + kb + quad*8;
                Vr[ht][0] = *(const short8*)(vr0);
                Vr[ht][1] = *(const short8*)(vr0 + 32);
                Vi[ht][0] = *(const short8*)(vi0);
                Vi[ht][1] = *(const short8*)(vi0 + 32);
            }

            float tm[4];
            #pragma unroll
            for (int r = 0; r < 4; ++r)
                tm[r] = fmaxf(fmaxf(mag[0][r], mag[1][r]), fmaxf(mag[2][r], mag[3][r]));
            #pragma unroll
            for (int d = 1; d < 16; d <<= 1)
                #pragma unroll
                for (int r = 0; r < 4; ++r)
                    tm[r] = fmaxf(tm[r], __shfl_xor(tm[r], d, 16));

            // defer-max: rescale only when running max grows past slack
            int need = (tm[0] > m[0] + 8.f) | (tm[1] > m[1] + 8.f) |
                       (tm[2] > m[2] + 8.f) | (tm[3] > m[3] + 8.f);
            if (__any(need)) {
                float al[4];
                #pragma unroll
                for (int r = 0; r < 4; ++r) {
                    float mn = fmaxf(m[r], tm[r]);
                    al[r] = __builtin_amdgcn_exp2f(m[r] - mn);
                    m[r] = mn;
                }
                #pragma unroll
                for (int h = 0; h < 4; ++h)
                    #pragma unroll
                    for (int r = 0; r < 4; ++r) { Or[h][r] *= al[r]; Oi[h][r] *= al[r]; }
                #pragma unroll
                for (int r = 0; r < 4; ++r) Ol[r] *= al[r];
            }

            #pragma unroll
            for (int nt = 0; nt < 4; ++nt)
                #pragma unroll
                for (int r = 0; r < 4; ++r) {
                    float p = __builtin_amdgcn_exp2f(mag[nt][r] - m[r]);
                    Pw[(quad*4 + r) * PLDS + nt*16 + lm] = f2bf_s(p);
                }
            short8 Af0 = *(const short8*)&Pw[lm * PLDS + quad*8];
            short8 Af1 = *(const short8*)&Pw[lm * PLDS + 32 + quad*8];

            __builtin_amdgcn_s_setprio(1);
            Ol = __builtin_amdgcn_mfma_f32_16x16x32_bf16(Af0, ones, Ol, 0,0,0);
            Ol = __builtin_amdgcn_mfma_f32_16x16x32_bf16(Af1, ones, Ol, 0,0,0);
            __builtin_amdgcn_s_setprio(0);

            #pragma unroll
            for (int ht = 0; ht < 4; ++ht) {
                __builtin_amdgcn_s_setprio(1);
                Or[ht] = __builtin_amdgcn_mfma_f32_16x16x32_bf16(Af0, Vr[ht][0], Or[ht], 0,0,0);
                Or[ht] = __builtin_amdgcn_mfma_f32_16x16x32_bf16(Af1, Vr[ht][1], Or[ht], 0,0,0);
                Oi[ht] = __builtin_amdgcn_mfma_f32_16x16x32_bf16(Af0, Vi[ht][0], Oi[ht], 0,0,0);
                Oi[ht] = __builtin_amdgcn_mfma_f32_16x16x32_bf16(Af1, Vi[ht][1], Oi[ht], 0,0,0);
                __builtin_amdgcn_s_setprio(0);
            }
        }

        __syncthreads();

        #pragma unroll
        for (int ht = 0; ht < 4; ++ht)
            #pragma unroll
            for (int r = 0; r < 4; ++r) {
                comb[wave][quad*4 + r][ht*16 + lm]      = Or[ht][r];
                comb[wave][quad*4 + r][64 + ht*16 + lm] = Oi[ht][r];
            }
        if (lm == 0) {
            #pragma unroll
            for (int r = 0; r < 4; ++r) {
                cmw[wave][quad*4 + r] = m[r];
                clw[wave][quad*4 + r] = Ol[r];
            }
        }
        __syncthreads();

        for (int e = tid; e < 16*128; e += 256) {
            int q = e >> 7, h = e & 127;
            float mstar = fmaxf(fmaxf(cmw[0][q], cmw[1][q]), fmaxf(cmw[2][q], cmw[3][q]));
            float osum = 0.f, lsum = 0.f;
            #pragma unroll
            for (int w = 0; w < 4; ++w) {
                float f = __builtin_amdgcn_exp2f(cmw[w][q] - mstar);
                osum = fmaf(f, comb[w][q][h], osum);
                lsum = fmaf(f, clw[w][q], lsum);
            }
            float res = osum / lsum;
            int comp = h >> 6, hh = h & 63;
            out[(size_t)comp * NST + ((size_t)(b*TT + qbase + q)) * HH + hh] = res;
        }

        __syncthreads();   // protect comb/cmw/clw reuse by the next tile
    }
}

extern "C" void kernel_launch(void* const* d_in, const int* in_sizes, int n_in,
                              void* d_out, int out_size, void* d_ws, size_t ws_size,
                              hipStream_t stream)
{
    const float* xr  = (const float*)d_in[0];
    const float* xi  = (const float*)d_in[1];
    const float* Wkr = (const float*)d_in[2];
    const float* Wki = (const float*)d_in[3];
    const float* Wqr = (const float*)d_in[4];
    const float* Wqi = (const float*)d_in[5];
    const float* Wvr = (const float*)d_in[6];
    const float* Wvi = (const float*)d_in[7];

    short* Bt = (short*)d_ws;                               // 1.5 MB
    short* G  = (short*)((char*)d_ws + (2u  << 20));        // 8 MB  [16384][256]
    short* VT = (short*)((char*)d_ws + (11u << 20));        // 4.3 MB [2][8][64][VTP]
    float* out = (float*)d_out;

    prep_kernel<<<NN, 256, 0, stream>>>(Wkr, Wki, Wqr, Wqi, Wvr, Wvi, Bt);

    dim3 g1(NROW / 128, 6);
    proj_gemm<<<g1, 256, 0, stream>>>(xr, xi, Bt, G, VT);

    dim3 g3(BB, TT / 32);   // bid%8 == b; block y does tiles 127-y and y
    attn_kernel<<<g3, 256, 0, stream>>>(G, VT, out);
}